// Round 10
// baseline (166.288 us; speedup 1.0000x reference)
//
#include <hip/hip_runtime.h>
#include <stdint.h>

#define L_SEQ 2048
#define BATCH 2
#define DMODEL 512
#define PROJ 1024
#define NST 32
#define NCAT 1152   // 1024 (Wd) + 32 (WB) + 32 (WC) + 64 zero pad -> 9*128
#define ROWS (BATCH*L_SEQ)  // 4096
#define THRESH 50.0f        // suffix cutoff (nats)

typedef float f32x4 __attribute__((ext_vector_type(4)));
typedef short short8 __attribute__((ext_vector_type(8)));

__device__ inline float bf2f(unsigned short u){ uint32_t x=((uint32_t)u)<<16; float f; __builtin_memcpy(&f,&x,4); return f; }
__device__ inline unsigned short f2bf(float f){ uint32_t x; __builtin_memcpy(&x,&f,4); uint32_t r=x+0x7FFFu+((x>>16)&1u); return (unsigned short)(r>>16); }
__device__ inline float siluf(float x){ return x/(1.f+__expf(-x)); }
__device__ inline float softplusf(float x){ return x>20.f? x : log1pf(__expf(x)); }

#define AS1(p) ((const __attribute__((address_space(1))) void*)(p))
#define AS3(p) ((__attribute__((address_space(3))) void*)(p))

template<int N> __device__ inline void wait_vmcnt(){
  if constexpr (N==0)      asm volatile("s_waitcnt vmcnt(0)" ::: "memory");
  else if constexpr (N==4) asm volatile("s_waitcnt vmcnt(4)" ::: "memory");
  else if constexpr (N==6) asm volatile("s_waitcnt vmcnt(6)" ::: "memory");
  else                     asm volatile("s_waitcnt vmcnt(8)" ::: "memory");
}

// ---------------- weight prep: fp32 -> bf16 transposed / concatenated ----------------
__global__ __launch_bounds__(256)
void prep_kernel(const float* __restrict__ W1, const float* __restrict__ b1,
                 const float* __restrict__ W2, const float* __restrict__ b2,
                 const float* __restrict__ Wd, const float* __restrict__ bd,
                 const float* __restrict__ WB, const float* __restrict__ bB,
                 const float* __restrict__ WC, const float* __restrict__ bC,
                 const float* __restrict__ W3,
                 unsigned short* __restrict__ W12t, unsigned short* __restrict__ Wcatt,
                 unsigned short* __restrict__ W3t, float* __restrict__ bias12,
                 float* __restrict__ biascat)
{
  int i = blockIdx.x*256 + threadIdx.x;
  const int nA = 2048*512;        // W12t [2048][512]
  const int nB = NCAT*1024;       // Wcatt [1152][1024]
  const int nC = 512*1024;        // W3t  [512][1024]
  if (i < nA) {
    int n = i >> 9, k = i & 511;
    float v = (n < 1024) ? W1[k*1024 + n] : W2[k*1024 + (n-1024)];
    W12t[i] = f2bf(v);
    return;
  }
  i -= nA;
  if (i < nB) {
    int n = i >> 10, k = i & 1023;
    float v;
    if (n < 1024) v = Wd[k*1024 + n];
    else if (n < 1056) v = WB[k*32 + (n-1024)];
    else if (n < 1088) v = WC[k*32 + (n-1056)];
    else v = 0.f;
    Wcatt[i] = f2bf(v);
    return;
  }
  i -= nB;
  if (i < nC) {
    int n = i >> 10, k = i & 1023;
    W3t[i] = f2bf(W3[k*512 + n]);
    return;
  }
  i -= nC;
  if (i < 2048) { bias12[i] = (i < 1024) ? b1[i] : b2[i-1024]; return; }
  i -= 2048;
  if (i < NCAT) {
    biascat[i] = (i < 1024) ? bd[i] : (i < 1056) ? bB[i-1024] : (i < 1088) ? bC[i-1056] : 0.f;
  }
}

// ---------------- LayerNorm: one wave per row of 512, write bf16 ----------------
__global__ __launch_bounds__(256)
void ln_kernel(const float* __restrict__ x, const float* __restrict__ gamma,
               const float* __restrict__ beta, unsigned short* __restrict__ H)
{
  int row = blockIdx.x*4 + (threadIdx.x >> 6);
  int lane = threadIdx.x & 63;
  const float4* xr = (const float4*)(x + (size_t)row*DMODEL);
  float4 v0 = xr[lane];
  float4 v1 = xr[lane+64];
  float s = v0.x+v0.y+v0.z+v0.w + v1.x+v1.y+v1.z+v1.w;
  float q = v0.x*v0.x+v0.y*v0.y+v0.z*v0.z+v0.w*v0.w
          + v1.x*v1.x+v1.y*v1.y+v1.z*v1.z+v1.w*v1.w;
#pragma unroll
  for (int m=32;m>0;m>>=1){ s += __shfl_xor(s,m); q += __shfl_xor(q,m); }
  float mu = s*(1.f/DMODEL);
  float var = q*(1.f/DMODEL) - mu*mu;
  float rs = rsqrtf(var + 1e-3f);
  int c0 = lane*4, c1 = 256 + lane*4;
  float4 g0 = *(const float4*)&gamma[c0]; float4 g1 = *(const float4*)&gamma[c1];
  float4 t0 = *(const float4*)&beta[c0];  float4 t1 = *(const float4*)&beta[c1];
  ushort4 o0, o1;
  o0.x = f2bf((v0.x-mu)*rs*g0.x + t0.x);
  o0.y = f2bf((v0.y-mu)*rs*g0.y + t0.y);
  o0.z = f2bf((v0.z-mu)*rs*g0.z + t0.z);
  o0.w = f2bf((v0.w-mu)*rs*g0.w + t0.w);
  o1.x = f2bf((v1.x-mu)*rs*g1.x + t1.x);
  o1.y = f2bf((v1.y-mu)*rs*g1.y + t1.y);
  o1.z = f2bf((v1.z-mu)*rs*g1.z + t1.z);
  o1.w = f2bf((v1.w-mu)*rs*g1.w + t1.w);
  *(ushort4*)&H[(size_t)row*DMODEL + c0] = o0;
  *(ushort4*)&H[(size_t)row*DMODEL + c1] = o1;
}

// ---------------- bf16 GEMM: BM x BN tile, BK=64, AM=BM/32 per-wave rows ----------------
// 256 thr, 2x2 waves (wave out = (BM/2) x (BN/2)), depth-2 prefetch, triple buffer,
// counted vmcnt. XCD-chunked swizzle (grid %8==0).
// MODE 1: +bias[col] -> bf16 (P12). MODE 2 (transposed): +bias[row], softplus row<1024,
//         out[row*ROWS+col] fp32 (CT). MODE 3: +bias[col]+res -> fp32 (d_out).
template<int BM, int BN, int MODE>
__global__ __launch_bounds__(256)
void gemm_bt(const unsigned short* __restrict__ A, const unsigned short* __restrict__ Bt,
             void* __restrict__ Cv, const float* __restrict__ bias,
             const float* __restrict__ res, int M, int N, int K)
{
  constexpr int BK = 64;
  constexpr int BMW = BM/2, BNW = BN/2;
  constexpr int AM = BMW/16, AN = BNW/16;
  constexpr int ASEGI = BM/32;              // gload_lds per thread for A per K-step
  constexpr int BSEGI = BN/32;
  constexpr int LPT = ASEGI + BSEGI;
  __shared__ unsigned short As[3][BM*BK];
  __shared__ unsigned short Bs[3][BN*BK];
  int tid = threadIdx.x;
  int lane = tid & 63, wid = tid >> 6;
  int wm = wid >> 1, wn = wid & 1;

  // XCD-chunked bijective swizzle
  int gx = gridDim.x;
  int nwg = gx * gridDim.y;
  int L = blockIdx.y*gx + blockIdx.x;
  int W = (L & 7)*(nwg >> 3) + (L >> 3);
  int bx = W % gx, by = W / gx;
  int m0 = bx*BM, n0 = by*BN;

  f32x4 acc[AM][AN];
#pragma unroll
  for (int i=0;i<AM;i++)
#pragma unroll
    for (int j=0;j<AN;j++)
#pragma unroll
      for (int e=0;e<4;e++) acc[i][j][e] = 0.f;

  // hoisted per-thread source pointers; LDS seg s=(row=s>>3, slot=s&7),
  // slot holds source k-chunk slot^(row&7)  [XOR swizzle on source]
  const unsigned short* ap[ASEGI];
  const unsigned short* bp[BSEGI];
#pragma unroll
  for (int j=0;j<ASEGI;j++){
    int s = tid + j*256;
    int row = s >> 3, kc = ((s & 7) ^ (row & 7)) * 8;
    ap[j] = A + (size_t)(m0+row)*K + kc;
  }
#pragma unroll
  for (int j=0;j<BSEGI;j++){
    int s = tid + j*256;
    int row = s >> 3, kc = ((s & 7) ^ (row & 7)) * 8;
    bp[j] = Bt + (size_t)(n0+row)*K + kc;
  }

  auto stage = [&](int buf){
#pragma unroll
    for (int j=0;j<ASEGI;j++){
      __builtin_amdgcn_global_load_lds(AS1(ap[j]), AS3(&As[buf][(size_t)(j*256 + wid*64)*8]), 16, 0, 0);
      ap[j] += BK;
    }
#pragma unroll
    for (int j=0;j<BSEGI;j++){
      __builtin_amdgcn_global_load_lds(AS1(bp[j]), AS3(&Bs[buf][(size_t)(j*256 + wid*64)*8]), 16, 0, 0);
      bp[j] += BK;
    }
  };

  stage(0);
  stage(1);
  int T = K/BK;
  int rb = 0, wb = 2;
  int r = lane & 15, kb = lane >> 4;
  for (int t = 0; t < T; ++t) {
    if (t+1 < T) wait_vmcnt<LPT>();    // stage(t) done; stage(t+1) in flight
    else         wait_vmcnt<0>();
    __builtin_amdgcn_s_barrier();
    if (t+2 < T) { stage(wb); wb = (wb==2)?0:wb+1; }
#pragma unroll
    for (int ks=0; ks<2; ++ks) {
      int cx = (ks*4 + kb) ^ (r & 7);
      short8 af[AM], bfr[AN];
#pragma unroll
      for (int i=0;i<AM;i++){
        int row = wm*BMW + i*16 + r;
        af[i] = *(const short8*)&As[rb][(row*8 + cx)*8];
      }
#pragma unroll
      for (int j=0;j<AN;j++){
        int row = wn*BNW + j*16 + r;
        bfr[j] = *(const short8*)&Bs[rb][(row*8 + cx)*8];
      }
#pragma unroll
      for (int i=0;i<AM;i++)
#pragma unroll
        for (int j=0;j<AN;j++)
          acc[i][j] = __builtin_amdgcn_mfma_f32_16x16x32_bf16(af[i], bfr[j], acc[i][j], 0,0,0);
    }
    rb = (rb==2)?0:rb+1;
  }

  int rr = (lane >> 4)*4, cc = lane & 15;
#pragma unroll
  for (int i=0;i<AM;i++)
#pragma unroll
    for (int j=0;j<AN;j++) {
      int col = n0 + wn*BNW + j*16 + cc;
      float bcol = (MODE == 2) ? 0.f : bias[col];
#pragma unroll
      for (int e=0;e<4;e++) {
        int row = m0 + wm*BMW + i*16 + rr + e;
        float v = acc[i][j][e];
        if constexpr (MODE == 2) {
          v += bias[row];
          if (row < 1024) v = softplusf(v);
          ((float*)Cv)[(size_t)row*N + col] = v;
        } else if constexpr (MODE == 1) {
          ((unsigned short*)Cv)[(size_t)row*N + col] = f2bf(v + bcol);
        } else {
          v += bcol + res[(size_t)row*N + col];
          ((float*)Cv)[(size_t)row*N + col] = v;
        }
      }
    }
}

// ---------------- causal depthwise conv (K=4) + SiLU; also SiLU for x2 (bf16 in) ----------------
__global__ __launch_bounds__(256)
void conv_silu_kernel(const unsigned short* __restrict__ P12, const float* __restrict__ ck,
                      const float* __restrict__ cb, unsigned short* __restrict__ ubf,
                      unsigned short* __restrict__ x2bf)
{
  int gid = blockIdx.x*256 + threadIdx.x;   // ROWS * 512 tasks
  int c4 = gid & 511;
  int row = gid >> 9;
  int l = row & (L_SEQ-1);
  if (c4 < 256) {
    int c = c4*4;
    float4 bv = *(const float4*)&cb[c];
    float r0=bv.x, r1=bv.y, r2=bv.z, r3=bv.w;
#pragma unroll
    for (int t=0;t<4;t++){
      int lsrc = l - 3 + t;
      if (lsrc >= 0) {
        ushort4 xv = *(const ushort4*)&P12[(size_t)(row-3+t)*2048 + c];
        float4 kv = *(const float4*)&ck[t*PROJ + c];
        r0 = fmaf(bf2f(xv.x),kv.x,r0);
        r1 = fmaf(bf2f(xv.y),kv.y,r1);
        r2 = fmaf(bf2f(xv.z),kv.z,r2);
        r3 = fmaf(bf2f(xv.w),kv.w,r3);
      }
    }
    ushort4 o;
    o.x=f2bf(siluf(r0)); o.y=f2bf(siluf(r1)); o.z=f2bf(siluf(r2)); o.w=f2bf(siluf(r3));
    *(ushort4*)&ubf[(size_t)row*PROJ + c] = o;
  } else {
    int c = (c4-256)*4;
    ushort4 xv = *(const ushort4*)&P12[(size_t)row*2048 + 1024 + c];
    ushort4 o;
    o.x=f2bf(siluf(bf2f(xv.x))); o.y=f2bf(siluf(bf2f(xv.y)));
    o.z=f2bf(siluf(bf2f(xv.z))); o.w=f2bf(siluf(bf2f(xv.w)));
    *(ushort4*)&x2bf[(size_t)row*PROJ + c] = o;
  }
}

// ---------------- fused suffix-sum + windowed gated scan ----------------
// Block = 8 groups (one per 32 lanes). Phase A: lane-blocked suffix pass (shfl-only)
// -> suf8 in LDS + l0. Phase B: batch-8 scan. ystate written as bf16.
__global__ __launch_bounds__(256)
void sscan_kernel(const float* __restrict__ CT, const unsigned short* __restrict__ ubf,
                  const float* __restrict__ A_log, int* __restrict__ l0out,
                  unsigned short* __restrict__ ystate)
{
  __shared__ float suf8sh[8][256];
  int tid = threadIdx.x;
  int n = tid & 31, gsub = tid >> 5;
  int G = blockIdx.x*8 + gsub;
  int b = G >> 10, d = G & 1023;
  const float* dT = CT + (size_t)d*ROWS + b*L_SEQ;   // softplus'd delta row

  // phase A: lane n owns elements [n*64, n*64+64)
  float mysum = 0.f;
  {
    const float4* c4 = (const float4*)(dT + n*64);
    for (int it=0; it<16; ++it){ float4 v = c4[it]; mysum += v.x+v.y+v.z+v.w; }
  }
  float incl = mysum;
#pragma unroll
  for (int dlt=1; dlt<32; dlt<<=1){ float t = __shfl_up(incl, dlt, 32); if (n >= dlt) incl += t; }
  float Tot = __shfl(incl, 31, 32);
  float excl = incl - mysum;
  int cnt = 0;
  {
    const float4* c4 = (const float4*)(dT + n*64);
    float run = excl;
    for (int it=0; it<16; ++it){
      float4 v = c4[it];
      if ((it & 1) == 0) suf8sh[gsub][n*8 + (it>>1)] = Tot - run;
      cnt += (Tot - run >= THRESH); run += v.x;
      cnt += (Tot - run >= THRESH); run += v.y;
      cnt += (Tot - run >= THRESH); run += v.z;
      cnt += (Tot - run >= THRESH); run += v.w;
    }
  }
#pragma unroll
  for (int m=16;m>0;m>>=1) cnt += __shfl_xor(cnt, m, 32);
  int myl0 = cnt > 0 ? cnt-1 : 0;
  if (n == 0) l0out[G] = myl0;
  __syncthreads();

  // phase B
  int base = min(myl0, __shfl_xor(myl0, 32)) & ~7;   // wave-uniform, 8-aligned
  float np1 = __expf(A_log[d*NST + n]);              // -A[d,n] = n+1
  const float* Br = CT + (size_t)(1024+n)*ROWS + b*L_SEQ;
  const float* Cr = CT + (size_t)(1056+n)*ROWS + b*L_SEQ;
  const unsigned short* ub = ubf + (size_t)b*L_SEQ*PROJ + d;
  unsigned short* yb = ystate + (size_t)b*L_SEQ*PROJ + d;
  float s = 0.f;
  for (int l = base; l < L_SEQ; l += 8) {
    float4 d0 = *(const float4*)&dT[l];
    float4 d1 = *(const float4*)&dT[l+4];
    float4 B0 = *(const float4*)&Br[l];
    float4 B1 = *(const float4*)&Br[l+4];
    float4 C0 = *(const float4*)&Cr[l];
    float4 C1 = *(const float4*)&Cr[l+4];
    float sufv = suf8sh[gsub][l >> 3];               // suffix incl. position l
    float dl[8] = {d0.x,d0.y,d0.z,d0.w,d1.x,d1.y,d1.z,d1.w};
    float Bv[8] = {B0.x,B0.y,B0.z,B0.w,B1.x,B1.y,B1.z,B1.w};
    float Cv[8] = {C0.x,C0.y,C0.z,C0.w,C1.x,C1.y,C1.z,C1.w};
    float uu[8];
#pragma unroll
    for (int t=0;t<8;t++) uu[t] = bf2f(ub[(size_t)(l+t)*PROJ]);
    float cum = 0.f;
#pragma unroll
    for (int t=0;t<8;t++){
      cum += dl[t];
      float decay = __expf(-dl[t]*np1);
      s = fmaf(decay, s, dl[t]*uu[t]*Bv[t]);
      float gte = 1.f/(1.f + 1e-12f*__expf(np1*(sufv - cum)));  // overflow->inf->0
      float contrib = s*gte*Cv[t];
#pragma unroll
      for (int m=16;m>0;m>>=1) contrib += __shfl_xor(contrib, m);
      if (n == 0) yb[(size_t)(l+t)*PROJ] = f2bf(contrib);
    }
  }
}

// ---------------- z = (ystate_gated + u*D_skip) * x2 -> bf16 (l0-gated) ----------------
__global__ __launch_bounds__(256)
void zmul_kernel(const unsigned short* __restrict__ ystate, const unsigned short* __restrict__ ubf,
                 const unsigned short* __restrict__ x2bf, const float* __restrict__ Dskip,
                 const int* __restrict__ l0arr, unsigned short* __restrict__ zbf)
{
  size_t i = ((size_t)blockIdx.x*256 + threadIdx.x)*4;
  int d = (int)(i & (PROJ-1));
  int row = (int)(i >> 10);
  int l = row & (L_SEQ-1);
  int b = row >> 11;
  int4 l0v = *(const int4*)&l0arr[b*PROJ + d];
  ushort4 yu = *(const ushort4*)&ystate[i];
  float ysx = (l >= l0v.x) ? bf2f(yu.x) : 0.f;
  float ysy = (l >= l0v.y) ? bf2f(yu.y) : 0.f;
  float ysz = (l >= l0v.z) ? bf2f(yu.z) : 0.f;
  float ysw = (l >= l0v.w) ? bf2f(yu.w) : 0.f;
  ushort4 uu = *(const ushort4*)&ubf[i];
  ushort4 xx = *(const ushort4*)&x2bf[i];
  float4 Dv = *(const float4*)&Dskip[d];
  ushort4 o;
  o.x = f2bf((ysx + bf2f(uu.x)*Dv.x)*bf2f(xx.x));
  o.y = f2bf((ysy + bf2f(uu.y)*Dv.y)*bf2f(xx.y));
  o.z = f2bf((ysz + bf2f(uu.z)*Dv.z)*bf2f(xx.z));
  o.w = f2bf((ysw + bf2f(uu.w)*Dv.w)*bf2f(xx.w));
  *(ushort4*)&zbf[i] = o;
}

extern "C" void kernel_launch(void* const* d_in, const int* in_sizes, int n_in,
                              void* d_out, int out_size, void* d_ws, size_t ws_size,
                              hipStream_t stream)
{
  const float* x     = (const float*)d_in[0];
  const float* ln_g  = (const float*)d_in[1];
  const float* ln_b  = (const float*)d_in[2];
  const float* W1    = (const float*)d_in[3];
  const float* b1    = (const float*)d_in[4];
  const float* W2    = (const float*)d_in[5];
  const float* b2    = (const float*)d_in[6];
  const float* convk = (const float*)d_in[7];
  const float* convb = (const float*)d_in[8];
  const float* A_log = (const float*)d_in[9];
  const float* Dskip = (const float*)d_in[10];
  const float* WB    = (const float*)d_in[11];
  const float* bB    = (const float*)d_in[12];
  const float* WC    = (const float*)d_in[13];
  const float* bC    = (const float*)d_in[14];
  const float* Wd    = (const float*)d_in[15];
  const float* bd    = (const float*)d_in[16];
  const float* W3    = (const float*)d_in[17];
  const float* b3    = (const float*)d_in[18];

  char* w = (char*)d_ws;
  auto alloc = [&](size_t bytes){ char* p = w; w += (bytes + 255) & ~(size_t)255; return p; };
  unsigned short* Hbf    = (unsigned short*)alloc((size_t)ROWS*DMODEL*2);
  unsigned short* W12t   = (unsigned short*)alloc((size_t)2048*512*2);
  unsigned short* Wcatt  = (unsigned short*)alloc((size_t)NCAT*1024*2);
  unsigned short* W3t    = (unsigned short*)alloc((size_t)512*1024*2);
  float*          bias12 = (float*)alloc(2048*4);
  float*          biascat= (float*)alloc(NCAT*4);
  unsigned short* P12    = (unsigned short*)alloc((size_t)ROWS*2048*2);
  unsigned short* ubf    = (unsigned short*)alloc((size_t)ROWS*PROJ*2);
  unsigned short* x2bf   = (unsigned short*)alloc((size_t)ROWS*PROJ*2);
  float*          CT     = (float*)alloc((size_t)NCAT*ROWS*4);   // transposed gemm2 out
  int*            l0arr  = (int*)alloc(2048*4);
  unsigned short* ystate = (unsigned short*)alloc((size_t)ROWS*PROJ*2);
  unsigned short* zbf    = (unsigned short*)alloc((size_t)ROWS*PROJ*2);

  {
    int total = 2048*512 + NCAT*1024 + 512*1024 + 2048 + NCAT;
    prep_kernel<<<(total+255)/256, 256, 0, stream>>>(W1,b1,W2,b2,Wd,bd,WB,bB,WC,bC,W3,
                                                     W12t,Wcatt,W3t,bias12,biascat);
  }
  ln_kernel<<<ROWS/4, 256, 0, stream>>>(x, ln_g, ln_b, Hbf);

  // gemm1: P12[4096][2048] = Hbf x W12t^T
  dim3 g1(ROWS/128, 2048/64);   // 32 x 32 = 1024 blocks
  gemm_bt<128,64,1><<<g1, 256, 0, stream>>>(Hbf, W12t, P12, bias12, nullptr, ROWS, 2048, DMODEL);

  conv_silu_kernel<<<ROWS*512/256, 256, 0, stream>>>(P12, convk, convb, ubf, x2bf);

  // gemm2 (transposed out): CT[1152][4096] = Wcatt x ubf^T
  dim3 g2(NCAT/128, ROWS/64);   // 9 x 64 = 576 blocks
  gemm_bt<128,64,2><<<g2, 256, 0, stream>>>(Wcatt, ubf, CT, biascat, nullptr, NCAT, ROWS, PROJ);

  // fused suffix + scan
  sscan_kernel<<<2048/8, 256, 0, stream>>>(CT, ubf, A_log, l0arr, ystate);

  zmul_kernel<<<(ROWS*PROJ/4)/256, 256, 0, stream>>>(ystate, ubf, x2bf, Dskip, l0arr, zbf);

  // gemm3: out[4096][512] = zbf x W3t^T + x
  dim3 g3(ROWS/128, DMODEL/64); // 32 x 8 = 256 blocks
  gemm_bt<128,64,3><<<g3, 256, 0, stream>>>(zbf, W3t, (float*)d_out, b3, x, ROWS, DMODEL, PROJ);
}

// Round 11
// 159.998 us; speedup vs baseline: 1.0393x; 1.0393x over previous
//
#include <hip/hip_runtime.h>
#include <stdint.h>

#define L_SEQ 2048
#define BATCH 2
#define DMODEL 512
#define PROJ 1024
#define NST 32
#define NCATU 1088  // 1024 (Wd) + 32 (WB) + 32 (WC) -> 17*64
#define ROWS (BATCH*L_SEQ)  // 4096
#define THRESH 50.0f        // suffix cutoff (nats)

typedef float f32x4 __attribute__((ext_vector_type(4)));
typedef short short8 __attribute__((ext_vector_type(8)));

__device__ inline float bf2f(unsigned short u){ uint32_t x=((uint32_t)u)<<16; float f; __builtin_memcpy(&f,&x,4); return f; }
__device__ inline unsigned short f2bf(float f){ uint32_t x; __builtin_memcpy(&x,&f,4); uint32_t r=x+0x7FFFu+((x>>16)&1u); return (unsigned short)(r>>16); }
__device__ inline float siluf(float x){ return x/(1.f+__expf(-x)); }
__device__ inline float softplusf(float x){ return x>20.f? x : log1pf(__expf(x)); }

#define AS1(p) ((const __attribute__((address_space(1))) void*)(p))
#define AS3(p) ((__attribute__((address_space(3))) void*)(p))

template<int N> __device__ inline void wait_vmcnt(){
  if constexpr (N==0)      asm volatile("s_waitcnt vmcnt(0)" ::: "memory");
  else if constexpr (N==4) asm volatile("s_waitcnt vmcnt(4)" ::: "memory");
  else                     asm volatile("s_waitcnt vmcnt(8)" ::: "memory");
}

// ---------------- weight prep: LDS-tiled transposes (coalesced both sides) ----------------
// tiles: [0,1024) W12t ; [1024,2112) Wcatt ; [2112,2624) W3t ; [2624,2637) biases
__global__ __launch_bounds__(256)
void prep_kernel(const float* __restrict__ W1, const float* __restrict__ b1,
                 const float* __restrict__ W2, const float* __restrict__ b2,
                 const float* __restrict__ Wd, const float* __restrict__ bd,
                 const float* __restrict__ WB, const float* __restrict__ bB,
                 const float* __restrict__ WC, const float* __restrict__ bC,
                 const float* __restrict__ W3,
                 unsigned short* __restrict__ W12t, unsigned short* __restrict__ Wcatt,
                 unsigned short* __restrict__ W3t, float* __restrict__ bias12,
                 float* __restrict__ biascat)
{
  __shared__ float tile[32][33];
  int bid = blockIdx.x;
  int lx = threadIdx.x & 31, ly = threadIdx.x >> 5;   // ly 0..7
  if (bid < 1024) {                    // W12t[2048][512] = (W1||W2)[512][2048]^T
    int kt = bid & 15, nt = bid >> 4;
    int k0 = kt*32, n0 = nt*32;
    const float* S = (n0 < 1024) ? W1 : W2;
    int nc = (n0 < 1024) ? n0 : n0 - 1024;
#pragma unroll
    for (int i=0;i<4;i++)
      tile[ly+i*8][lx] = S[(size_t)(k0+ly+i*8)*1024 + nc + lx];
    __syncthreads();
#pragma unroll
    for (int i=0;i<4;i++)
      W12t[(size_t)(n0+ly+i*8)*512 + k0 + lx] = f2bf(tile[lx][ly+i*8]);
    return;
  }
  if (bid < 2112) {                    // Wcatt[1088][1024] = (Wd|WB|WC)[1024][1088]^T
    int t = bid - 1024;
    int kt = t & 31, nt = t >> 5;      // 32 k-tiles, 34 n-tiles
    int k0 = kt*32, n0 = nt*32;
#pragma unroll
    for (int i=0;i<4;i++){
      int k = k0 + ly + i*8;
      float v;
      if (n0 < 1024)       v = Wd[(size_t)k*1024 + n0 + lx];
      else if (n0 == 1024) v = WB[(size_t)k*32 + lx];
      else                 v = WC[(size_t)k*32 + lx];
      tile[ly+i*8][lx] = v;
    }
    __syncthreads();
#pragma unroll
    for (int i=0;i<4;i++)
      Wcatt[(size_t)(n0+ly+i*8)*1024 + k0 + lx] = f2bf(tile[lx][ly+i*8]);
    return;
  }
  if (bid < 2624) {                    // W3t[512][1024] = W3[1024][512]^T
    int t = bid - 2112;
    int kt = t & 31, nt = t >> 5;      // 32 k-tiles, 16 n-tiles
    int k0 = kt*32, n0 = nt*32;
#pragma unroll
    for (int i=0;i<4;i++)
      tile[ly+i*8][lx] = W3[(size_t)(k0+ly+i*8)*512 + n0 + lx];
    __syncthreads();
#pragma unroll
    for (int i=0;i<4;i++)
      W3t[(size_t)(n0+ly+i*8)*1024 + k0 + lx] = f2bf(tile[lx][ly+i*8]);
    return;
  }
  int j = (bid - 2624)*256 + threadIdx.x;
  if (j < 2048) { bias12[j] = (j < 1024) ? b1[j] : b2[j-1024]; return; }
  j -= 2048;
  if (j < NCATU) biascat[j] = (j < 1024) ? bd[j] : (j < 1056) ? bB[j-1024] : bC[j-1056];
}

// ---------------- LayerNorm: one wave per row of 512, write bf16 ----------------
__global__ __launch_bounds__(256)
void ln_kernel(const float* __restrict__ x, const float* __restrict__ gamma,
               const float* __restrict__ beta, unsigned short* __restrict__ H)
{
  int row = blockIdx.x*4 + (threadIdx.x >> 6);
  int lane = threadIdx.x & 63;
  const float4* xr = (const float4*)(x + (size_t)row*DMODEL);
  float4 v0 = xr[lane];
  float4 v1 = xr[lane+64];
  float s = v0.x+v0.y+v0.z+v0.w + v1.x+v1.y+v1.z+v1.w;
  float q = v0.x*v0.x+v0.y*v0.y+v0.z*v0.z+v0.w*v0.w
          + v1.x*v1.x+v1.y*v1.y+v1.z*v1.z+v1.w*v1.w;
#pragma unroll
  for (int m=32;m>0;m>>=1){ s += __shfl_xor(s,m); q += __shfl_xor(q,m); }
  float mu = s*(1.f/DMODEL);
  float var = q*(1.f/DMODEL) - mu*mu;
  float rs = rsqrtf(var + 1e-3f);
  int c0 = lane*4, c1 = 256 + lane*4;
  float4 g0 = *(const float4*)&gamma[c0]; float4 g1 = *(const float4*)&gamma[c1];
  float4 t0 = *(const float4*)&beta[c0];  float4 t1 = *(const float4*)&beta[c1];
  ushort4 o0, o1;
  o0.x = f2bf((v0.x-mu)*rs*g0.x + t0.x);
  o0.y = f2bf((v0.y-mu)*rs*g0.y + t0.y);
  o0.z = f2bf((v0.z-mu)*rs*g0.z + t0.z);
  o0.w = f2bf((v0.w-mu)*rs*g0.w + t0.w);
  o1.x = f2bf((v1.x-mu)*rs*g1.x + t1.x);
  o1.y = f2bf((v1.y-mu)*rs*g1.y + t1.y);
  o1.z = f2bf((v1.z-mu)*rs*g1.z + t1.z);
  o1.w = f2bf((v1.w-mu)*rs*g1.w + t1.w);
  *(ushort4*)&H[(size_t)row*DMODEL + c0] = o0;
  *(ushort4*)&H[(size_t)row*DMODEL + c1] = o1;
}

// ---------------- bf16 GEMM (r8 structure): 64x64, BK=64, depth-2, triple buffer ----------------
// A[M,Kfull] x Bt[N,Kfull]^T over K columns starting at blockIdx.z*K -> C or partial.
// MODE 1: +bias[col] -> bf16 (P12). MODE 2 (transposed): +bias[row], softplus row<1024 -> fp32 CT.
// MODE 5: raw fp32 partial at Cv + z*M*N (split-K).
template<int MODE>
__global__ __launch_bounds__(256)
void gemm_bt(const unsigned short* __restrict__ A, const unsigned short* __restrict__ Bt,
             void* __restrict__ Cv, const float* __restrict__ bias,
             const float* __restrict__ res, int M, int N, int K, int Kfull)
{
  constexpr int BK = 64;
  constexpr int LPT = 4;
  __shared__ unsigned short As[3][64*BK];
  __shared__ unsigned short Bs[3][64*BK];
  int tid = threadIdx.x;
  int lane = tid & 63, wid = tid >> 6;
  int wm = wid >> 1, wn = wid & 1;

  // XCD-chunked bijective swizzle (x,y only; grid.x*grid.y % 8 == 0)
  int gx = gridDim.x;
  int nwg = gx * gridDim.y;
  int L = blockIdx.y*gx + blockIdx.x;
  int W = (L & 7)*(nwg >> 3) + (L >> 3);
  int bx = W % gx, by = W / gx;
  int m0 = bx*64, n0 = by*64;
  int kofs = blockIdx.z*K;

  f32x4 acc[2][2];
#pragma unroll
  for (int i=0;i<2;i++)
#pragma unroll
    for (int j=0;j<2;j++)
#pragma unroll
      for (int e=0;e<4;e++) acc[i][j][e] = 0.f;

  // hoisted per-thread source pointers; LDS seg s=(row=s>>3, slot=s&7),
  // slot holds source k-chunk slot^(row&7)  [XOR swizzle on source]
  const unsigned short* ap[2];
  const unsigned short* bp[2];
#pragma unroll
  for (int j=0;j<2;j++){
    int s = tid + j*256;
    int row = s >> 3, kc = ((s & 7) ^ (row & 7)) * 8;
    ap[j] = A + (size_t)(m0+row)*Kfull + kofs + kc;
    bp[j] = Bt + (size_t)(n0+row)*Kfull + kofs + kc;
  }

  auto stage = [&](int buf){
#pragma unroll
    for (int j=0;j<2;j++){
      __builtin_amdgcn_global_load_lds(AS1(ap[j]), AS3(&As[buf][(size_t)(j*256 + wid*64)*8]), 16, 0, 0);
      ap[j] += BK;
    }
#pragma unroll
    for (int j=0;j<2;j++){
      __builtin_amdgcn_global_load_lds(AS1(bp[j]), AS3(&Bs[buf][(size_t)(j*256 + wid*64)*8]), 16, 0, 0);
      bp[j] += BK;
    }
  };

  stage(0);
  stage(1);
  int T = K/BK;
  int rb = 0, wb = 2;
  int r = lane & 15, kb = lane >> 4;
  for (int t = 0; t < T; ++t) {
    if (t+1 < T) wait_vmcnt<LPT>();    // stage(t) done; stage(t+1) in flight
    else         wait_vmcnt<0>();
    __builtin_amdgcn_s_barrier();
    if (t+2 < T) { stage(wb); wb = (wb==2)?0:wb+1; }
#pragma unroll
    for (int ks=0; ks<2; ++ks) {
      int cx = (ks*4 + kb) ^ (r & 7);
      short8 af[2], bfr[2];
#pragma unroll
      for (int i=0;i<2;i++){
        int row = wm*32 + i*16 + r;
        af[i] = *(const short8*)&As[rb][(row*8 + cx)*8];
      }
#pragma unroll
      for (int j=0;j<2;j++){
        int row = wn*32 + j*16 + r;
        bfr[j] = *(const short8*)&Bs[rb][(row*8 + cx)*8];
      }
      __builtin_amdgcn_s_setprio(1);
#pragma unroll
      for (int i=0;i<2;i++)
#pragma unroll
        for (int j=0;j<2;j++)
          acc[i][j] = __builtin_amdgcn_mfma_f32_16x16x32_bf16(af[i], bfr[j], acc[i][j], 0,0,0);
      __builtin_amdgcn_s_setprio(0);
    }
    rb = (rb==2)?0:rb+1;
  }

  int rr = (lane >> 4)*4, cc = lane & 15;
#pragma unroll
  for (int i=0;i<2;i++)
#pragma unroll
    for (int j=0;j<2;j++) {
      int col = n0 + wn*32 + j*16 + cc;
      float bcol = (MODE == 1) ? bias[col] : 0.f;
#pragma unroll
      for (int e=0;e<4;e++) {
        int row = m0 + wm*32 + i*16 + rr + e;
        float v = acc[i][j][e];
        if constexpr (MODE == 2) {
          v += bias[row];
          if (row < 1024) v = softplusf(v);
          ((float*)Cv)[(size_t)row*N + col] = v;
        } else if constexpr (MODE == 1) {
          ((unsigned short*)Cv)[(size_t)row*N + col] = f2bf(v + bcol);
        } else {  // MODE 5: raw partial
          ((float*)Cv)[(size_t)blockIdx.z*M*N + (size_t)row*N + col] = v;
        }
      }
    }
}

// ---------------- split-K reduce + bias + residual ----------------
__global__ __launch_bounds__(256)
void reduce_kernel(const float* __restrict__ P, const float* __restrict__ x,
                   const float* __restrict__ b3, float* __restrict__ out)
{
  size_t i = ((size_t)blockIdx.x*256 + threadIdx.x)*4;
  int col = (int)(i & 511);
  float4 a = *(const float4*)&P[i];
  float4 b = *(const float4*)&P[(size_t)ROWS*512 + i];
  float4 xv = *(const float4*)&x[i];
  float4 bv = *(const float4*)&b3[col];
  float4 o;
  o.x = a.x + b.x + xv.x + bv.x;
  o.y = a.y + b.y + xv.y + bv.y;
  o.z = a.z + b.z + xv.z + bv.z;
  o.w = a.w + b.w + xv.w + bv.w;
  *(float4*)&out[i] = o;
}

// ---------------- causal depthwise conv (K=4) + SiLU; also SiLU for x2 (bf16 in) ----------------
__global__ __launch_bounds__(256)
void conv_silu_kernel(const unsigned short* __restrict__ P12, const float* __restrict__ ck,
                      const float* __restrict__ cb, unsigned short* __restrict__ ubf,
                      unsigned short* __restrict__ x2bf)
{
  int gid = blockIdx.x*256 + threadIdx.x;   // ROWS * 512 tasks
  int c4 = gid & 511;
  int row = gid >> 9;
  int l = row & (L_SEQ-1);
  if (c4 < 256) {
    int c = c4*4;
    float4 bv = *(const float4*)&cb[c];
    float r0=bv.x, r1=bv.y, r2=bv.z, r3=bv.w;
#pragma unroll
    for (int t=0;t<4;t++){
      int lsrc = l - 3 + t;
      if (lsrc >= 0) {
        ushort4 xv = *(const ushort4*)&P12[(size_t)(row-3+t)*2048 + c];
        float4 kv = *(const float4*)&ck[t*PROJ + c];
        r0 = fmaf(bf2f(xv.x),kv.x,r0);
        r1 = fmaf(bf2f(xv.y),kv.y,r1);
        r2 = fmaf(bf2f(xv.z),kv.z,r2);
        r3 = fmaf(bf2f(xv.w),kv.w,r3);
      }
    }
    ushort4 o;
    o.x=f2bf(siluf(r0)); o.y=f2bf(siluf(r1)); o.z=f2bf(siluf(r2)); o.w=f2bf(siluf(r3));
    *(ushort4*)&ubf[(size_t)row*PROJ + c] = o;
  } else {
    int c = (c4-256)*4;
    ushort4 xv = *(const ushort4*)&P12[(size_t)row*2048 + 1024 + c];
    ushort4 o;
    o.x=f2bf(siluf(bf2f(xv.x))); o.y=f2bf(siluf(bf2f(xv.y)));
    o.z=f2bf(siluf(bf2f(xv.z))); o.w=f2bf(siluf(bf2f(xv.w)));
    *(ushort4*)&x2bf[(size_t)row*PROJ + c] = o;
  }
}

// ---------------- fused suffix-sum + windowed gated scan (bf16 ystate) ----------------
__global__ __launch_bounds__(256)
void sscan_kernel(const float* __restrict__ CT, const unsigned short* __restrict__ ubf,
                  const float* __restrict__ A_log, int* __restrict__ l0out,
                  unsigned short* __restrict__ ystate)
{
  __shared__ float suf8sh[8][256];
  int tid = threadIdx.x;
  int n = tid & 31, gsub = tid >> 5;
  int G = blockIdx.x*8 + gsub;
  int b = G >> 10, d = G & 1023;
  const float* dT = CT + (size_t)d*ROWS + b*L_SEQ;   // softplus'd delta row

  // phase A: lane n owns elements [n*64, n*64+64)
  float mysum = 0.f;
  {
    const float4* c4 = (const float4*)(dT + n*64);
    for (int it=0; it<16; ++it){ float4 v = c4[it]; mysum += v.x+v.y+v.z+v.w; }
  }
  float incl = mysum;
#pragma unroll
  for (int dlt=1; dlt<32; dlt<<=1){ float t = __shfl_up(incl, dlt, 32); if (n >= dlt) incl += t; }
  float Tot = __shfl(incl, 31, 32);
  float excl = incl - mysum;
  int cnt = 0;
  {
    const float4* c4 = (const float4*)(dT + n*64);
    float run = excl;
    for (int it=0; it<16; ++it){
      float4 v = c4[it];
      if ((it & 1) == 0) suf8sh[gsub][n*8 + (it>>1)] = Tot - run;
      cnt += (Tot - run >= THRESH); run += v.x;
      cnt += (Tot - run >= THRESH); run += v.y;
      cnt += (Tot - run >= THRESH); run += v.z;
      cnt += (Tot - run >= THRESH); run += v.w;
    }
  }
#pragma unroll
  for (int m=16;m>0;m>>=1) cnt += __shfl_xor(cnt, m, 32);
  int myl0 = cnt > 0 ? cnt-1 : 0;
  if (n == 0) l0out[G] = myl0;
  __syncthreads();

  // phase B
  int base = min(myl0, __shfl_xor(myl0, 32)) & ~7;   // wave-uniform, 8-aligned
  float np1 = __expf(A_log[d*NST + n]);              // -A[d,n] = n+1
  const float* Br = CT + (size_t)(1024+n)*ROWS + b*L_SEQ;
  const float* Cr = CT + (size_t)(1056+n)*ROWS + b*L_SEQ;
  const unsigned short* ub = ubf + (size_t)b*L_SEQ*PROJ + d;
  unsigned short* yb = ystate + (size_t)b*L_SEQ*PROJ + d;
  float s = 0.f;
  for (int l = base; l < L_SEQ; l += 8) {
    float4 d0 = *(const float4*)&dT[l];
    float4 d1 = *(const float4*)&dT[l+4];
    float4 B0 = *(const float4*)&Br[l];
    float4 B1 = *(const float4*)&Br[l+4];
    float4 C0 = *(const float4*)&Cr[l];
    float4 C1 = *(const float4*)&Cr[l+4];
    float sufv = suf8sh[gsub][l >> 3];               // suffix incl. position l
    float dl[8] = {d0.x,d0.y,d0.z,d0.w,d1.x,d1.y,d1.z,d1.w};
    float Bv[8] = {B0.x,B0.y,B0.z,B0.w,B1.x,B1.y,B1.z,B1.w};
    float Cv[8] = {C0.x,C0.y,C0.z,C0.w,C1.x,C1.y,C1.z,C1.w};
    float uu[8];
#pragma unroll
    for (int t=0;t<8;t++) uu[t] = bf2f(ub[(size_t)(l+t)*PROJ]);
    float cum = 0.f;
#pragma unroll
    for (int t=0;t<8;t++){
      cum += dl[t];
      float decay = __expf(-dl[t]*np1);
      s = fmaf(decay, s, dl[t]*uu[t]*Bv[t]);
      float gte = 1.f/(1.f + 1e-12f*__expf(np1*(sufv - cum)));  // overflow->inf->0
      float contrib = s*gte*Cv[t];
#pragma unroll
      for (int m=16;m>0;m>>=1) contrib += __shfl_xor(contrib, m);
      if (n == 0) yb[(size_t)(l+t)*PROJ] = f2bf(contrib);
    }
  }
}

// ---------------- z = (ystate_gated + u*D_skip) * x2 -> bf16 (l0-gated) ----------------
__global__ __launch_bounds__(256)
void zmul_kernel(const unsigned short* __restrict__ ystate, const unsigned short* __restrict__ ubf,
                 const unsigned short* __restrict__ x2bf, const float* __restrict__ Dskip,
                 const int* __restrict__ l0arr, unsigned short* __restrict__ zbf)
{
  size_t i = ((size_t)blockIdx.x*256 + threadIdx.x)*4;
  int d = (int)(i & (PROJ-1));
  int row = (int)(i >> 10);
  int l = row & (L_SEQ-1);
  int b = row >> 11;
  int4 l0v = *(const int4*)&l0arr[b*PROJ + d];
  ushort4 yu = *(const ushort4*)&ystate[i];
  float ysx = (l >= l0v.x) ? bf2f(yu.x) : 0.f;
  float ysy = (l >= l0v.y) ? bf2f(yu.y) : 0.f;
  float ysz = (l >= l0v.z) ? bf2f(yu.z) : 0.f;
  float ysw = (l >= l0v.w) ? bf2f(yu.w) : 0.f;
  ushort4 uu = *(const ushort4*)&ubf[i];
  ushort4 xx = *(const ushort4*)&x2bf[i];
  float4 Dv = *(const float4*)&Dskip[d];
  ushort4 o;
  o.x = f2bf((ysx + bf2f(uu.x)*Dv.x)*bf2f(xx.x));
  o.y = f2bf((ysy + bf2f(uu.y)*Dv.y)*bf2f(xx.y));
  o.z = f2bf((ysz + bf2f(uu.z)*Dv.z)*bf2f(xx.z));
  o.w = f2bf((ysw + bf2f(uu.w)*Dv.w)*bf2f(xx.w));
  *(ushort4*)&zbf[i] = o;
}

extern "C" void kernel_launch(void* const* d_in, const int* in_sizes, int n_in,
                              void* d_out, int out_size, void* d_ws, size_t ws_size,
                              hipStream_t stream)
{
  const float* x     = (const float*)d_in[0];
  const float* ln_g  = (const float*)d_in[1];
  const float* ln_b  = (const float*)d_in[2];
  const float* W1    = (const float*)d_in[3];
  const float* b1    = (const float*)d_in[4];
  const float* W2    = (const float*)d_in[5];
  const float* b2    = (const float*)d_in[6];
  const float* convk = (const float*)d_in[7];
  const float* convb = (const float*)d_in[8];
  const float* A_log = (const float*)d_in[9];
  const float* Dskip = (const float*)d_in[10];
  const float* WB    = (const float*)d_in[11];
  const float* bB    = (const float*)d_in[12];
  const float* WC    = (const float*)d_in[13];
  const float* bC    = (const float*)d_in[14];
  const float* Wd    = (const float*)d_in[15];
  const float* bd    = (const float*)d_in[16];
  const float* W3    = (const float*)d_in[17];
  const float* b3    = (const float*)d_in[18];

  char* w = (char*)d_ws;
  auto alloc = [&](size_t bytes){ char* p = w; w += (bytes + 255) & ~(size_t)255; return p; };
  unsigned short* Hbf    = (unsigned short*)alloc((size_t)ROWS*DMODEL*2);
  unsigned short* W12t   = (unsigned short*)alloc((size_t)2048*512*2);
  unsigned short* Wcatt  = (unsigned short*)alloc((size_t)NCATU*1024*2);
  unsigned short* W3t    = (unsigned short*)alloc((size_t)512*1024*2);
  float*          bias12 = (float*)alloc(2048*4);
  float*          biascat= (float*)alloc(NCATU*4);
  unsigned short* P12    = (unsigned short*)alloc((size_t)ROWS*2048*2);
  unsigned short* ubf    = (unsigned short*)alloc((size_t)ROWS*PROJ*2);
  unsigned short* x2bf   = (unsigned short*)alloc((size_t)ROWS*PROJ*2);
  float*          CT     = (float*)alloc((size_t)NCATU*ROWS*4);   // transposed gemm2 out
  int*            l0arr  = (int*)alloc(2048*4);
  unsigned short* ystate = (unsigned short*)alloc((size_t)ROWS*PROJ*2);
  unsigned short* zbf    = (unsigned short*)alloc((size_t)ROWS*PROJ*2);
  float*          Pp     = (float*)alloc((size_t)2*ROWS*512*4);   // split-K partials

  prep_kernel<<<2637, 256, 0, stream>>>(W1,b1,W2,b2,Wd,bd,WB,bB,WC,bC,W3,
                                        W12t,Wcatt,W3t,bias12,biascat);
  ln_kernel<<<ROWS/4, 256, 0, stream>>>(x, ln_g, ln_b, Hbf);

  // gemm1: P12[4096][2048] = Hbf x W12t^T   (2048 blocks, 8/CU)
  dim3 g1(ROWS/64, 2048/64);
  gemm_bt<1><<<g1, 256, 0, stream>>>(Hbf, W12t, P12, bias12, nullptr, ROWS, 2048, DMODEL, DMODEL);

  conv_silu_kernel<<<ROWS*512/256, 256, 0, stream>>>(P12, convk, convb, ubf, x2bf);

  // gemm2 (transposed out): CT[1088][4096] = Wcatt x ubf^T   (1088 blocks)
  dim3 g2(NCATU/64, ROWS/64);
  gemm_bt<2><<<g2, 256, 0, stream>>>(Wcatt, ubf, CT, biascat, nullptr, NCATU, ROWS, PROJ, PROJ);

  // fused suffix + scan
  sscan_kernel<<<2048/8, 256, 0, stream>>>(CT, ubf, A_log, l0arr, ystate);

  zmul_kernel<<<(ROWS*PROJ/4)/256, 256, 0, stream>>>(ystate, ubf, x2bf, Dskip, l0arr, zbf);

  // gemm3 split-K=2: partials (1024 blocks, 4/CU), then reduce(+bias+residual)
  dim3 g3(ROWS/64, 512/64, 2);
  gemm_bt<5><<<g3, 256, 0, stream>>>(zbf, W3t, Pp, b3, nullptr, ROWS, 512, 512, PROJ);
  reduce_kernel<<<(ROWS*512/4)/256, 256, 0, stream>>>(Pp, x, b3, (float*)d_out);
}

// Round 12
// 159.840 us; speedup vs baseline: 1.0403x; 1.0010x over previous
//
#include <hip/hip_runtime.h>
#include <stdint.h>

#define L_SEQ 2048
#define BATCH 2
#define DMODEL 512
#define PROJ 1024
#define NST 32
#define NCAT 1152   // 1024 (Wd) + 32 (WB) + 32 (WC) + 64 zero pad -> 9*128
#define ROWS (BATCH*L_SEQ)  // 4096
#define THRESH 50.0f        // suffix cutoff (nats)

typedef float f32x4 __attribute__((ext_vector_type(4)));
typedef short short8 __attribute__((ext_vector_type(8)));

__device__ inline float bf2f(unsigned short u){ uint32_t x=((uint32_t)u)<<16; float f; __builtin_memcpy(&f,&x,4); return f; }
__device__ inline unsigned short f2bf(float f){ uint32_t x; __builtin_memcpy(&x,&f,4); uint32_t r=x+0x7FFFu+((x>>16)&1u); return (unsigned short)(r>>16); }
__device__ inline float siluf(float x){ return x/(1.f+__expf(-x)); }
__device__ inline float softplusf(float x){ return x>20.f? x : log1pf(__expf(x)); }

#define AS1(p) ((const __attribute__((address_space(1))) void*)(p))
#define AS3(p) ((__attribute__((address_space(3))) void*)(p))

template<int N> __device__ inline void wait_vmcnt(){
  if constexpr (N==0)      asm volatile("s_waitcnt vmcnt(0)" ::: "memory");
  else if constexpr (N==4) asm volatile("s_waitcnt vmcnt(4)" ::: "memory");
  else if constexpr (N==8) asm volatile("s_waitcnt vmcnt(8)" ::: "memory");
  else                     asm volatile("s_waitcnt vmcnt(12)" ::: "memory");
}

// ---------------- weight prep: LDS-tiled transposes (coalesced both sides) ----------------
// blocks: [0,1024) W12t ; [1024,2176) Wcatt ; [2176,2688) W3t ; [2688,2701) biases
__global__ __launch_bounds__(256)
void prep_kernel(const float* __restrict__ W1, const float* __restrict__ b1,
                 const float* __restrict__ W2, const float* __restrict__ b2,
                 const float* __restrict__ Wd, const float* __restrict__ bd,
                 const float* __restrict__ WB, const float* __restrict__ bB,
                 const float* __restrict__ WC, const float* __restrict__ bC,
                 const float* __restrict__ W3,
                 unsigned short* __restrict__ W12t, unsigned short* __restrict__ Wcatt,
                 unsigned short* __restrict__ W3t, float* __restrict__ bias12,
                 float* __restrict__ biascat)
{
  __shared__ float tile[32][33];
  int bid = blockIdx.x;
  int lx = threadIdx.x & 31, ly = threadIdx.x >> 5;   // ly 0..7
  if (bid < 1024) {                    // W12t[2048][512] = (W1||W2)[512][2048]^T
    int kt = bid & 15, nt = bid >> 4;
    int k0 = kt*32, n0 = nt*32;
    const float* S = (n0 < 1024) ? W1 : W2;
    int nc = (n0 < 1024) ? n0 : n0 - 1024;
#pragma unroll
    for (int i=0;i<4;i++)
      tile[ly+i*8][lx] = S[(size_t)(k0+ly+i*8)*1024 + nc + lx];
    __syncthreads();
#pragma unroll
    for (int i=0;i<4;i++)
      W12t[(size_t)(n0+ly+i*8)*512 + k0 + lx] = f2bf(tile[lx][ly+i*8]);
    return;
  }
  if (bid < 2176) {                    // Wcatt[1152][1024] = (Wd|WB|WC|0)[1024][1152]^T
    int t = bid - 1024;
    int kt = t & 31, nt = t >> 5;      // 32 k-tiles, 36 n-tiles
    int k0 = kt*32, n0 = nt*32;
#pragma unroll
    for (int i=0;i<4;i++){
      int k = k0 + ly + i*8;
      float v;
      if (n0 < 1024)       v = Wd[(size_t)k*1024 + n0 + lx];
      else if (n0 == 1024) v = WB[(size_t)k*32 + lx];
      else if (n0 == 1056) v = WC[(size_t)k*32 + lx];
      else                 v = 0.f;
      tile[ly+i*8][lx] = v;
    }
    __syncthreads();
#pragma unroll
    for (int i=0;i<4;i++)
      Wcatt[(size_t)(n0+ly+i*8)*1024 + k0 + lx] = f2bf(tile[lx][ly+i*8]);
    return;
  }
  if (bid < 2688) {                    // W3t[512][1024] = W3[1024][512]^T
    int t = bid - 2176;
    int kt = t & 31, nt = t >> 5;      // 32 k-tiles, 16 n-tiles
    int k0 = kt*32, n0 = nt*32;
#pragma unroll
    for (int i=0;i<4;i++)
      tile[ly+i*8][lx] = W3[(size_t)(k0+ly+i*8)*512 + n0 + lx];
    __syncthreads();
#pragma unroll
    for (int i=0;i<4;i++)
      W3t[(size_t)(n0+ly+i*8)*1024 + k0 + lx] = f2bf(tile[lx][ly+i*8]);
    return;
  }
  int j = (bid - 2688)*256 + threadIdx.x;
  if (j < 2048) { bias12[j] = (j < 1024) ? b1[j] : b2[j-1024]; return; }
  j -= 2048;
  if (j < NCAT) biascat[j] = (j < 1024) ? bd[j] : (j < 1056) ? bB[j-1024] : (j < 1088) ? bC[j-1056] : 0.f;
}

// ---------------- LayerNorm: one wave per row of 512, write bf16 ----------------
__global__ __launch_bounds__(256)
void ln_kernel(const float* __restrict__ x, const float* __restrict__ gamma,
               const float* __restrict__ beta, unsigned short* __restrict__ H)
{
  int row = blockIdx.x*4 + (threadIdx.x >> 6);
  int lane = threadIdx.x & 63;
  const float4* xr = (const float4*)(x + (size_t)row*DMODEL);
  float4 v0 = xr[lane];
  float4 v1 = xr[lane+64];
  float s = v0.x+v0.y+v0.z+v0.w + v1.x+v1.y+v1.z+v1.w;
  float q = v0.x*v0.x+v0.y*v0.y+v0.z*v0.z+v0.w*v0.w
          + v1.x*v1.x+v1.y*v1.y+v1.z*v1.z+v1.w*v1.w;
#pragma unroll
  for (int m=32;m>0;m>>=1){ s += __shfl_xor(s,m); q += __shfl_xor(q,m); }
  float mu = s*(1.f/DMODEL);
  float var = q*(1.f/DMODEL) - mu*mu;
  float rs = rsqrtf(var + 1e-3f);
  int c0 = lane*4, c1 = 256 + lane*4;
  float4 g0 = *(const float4*)&gamma[c0]; float4 g1 = *(const float4*)&gamma[c1];
  float4 t0 = *(const float4*)&beta[c0];  float4 t1 = *(const float4*)&beta[c1];
  ushort4 o0, o1;
  o0.x = f2bf((v0.x-mu)*rs*g0.x + t0.x);
  o0.y = f2bf((v0.y-mu)*rs*g0.y + t0.y);
  o0.z = f2bf((v0.z-mu)*rs*g0.z + t0.z);
  o0.w = f2bf((v0.w-mu)*rs*g0.w + t0.w);
  o1.x = f2bf((v1.x-mu)*rs*g1.x + t1.x);
  o1.y = f2bf((v1.y-mu)*rs*g1.y + t1.y);
  o1.z = f2bf((v1.z-mu)*rs*g1.z + t1.z);
  o1.w = f2bf((v1.w-mu)*rs*g1.w + t1.w);
  *(ushort4*)&H[(size_t)row*DMODEL + c0] = o0;
  *(ushort4*)&H[(size_t)row*DMODEL + c1] = o1;
}

// ---------------- 128x128 bf16 GEMM: BK=64, double-buffer, counted vmcnt, 2 barriers ----------------
// staged bytes = 2*M*N*K*(1/128+1/128) -- half the 64^2 scheme. 64KB LDS -> 2 blocks/CU.
// MODE 1: +bias[col] -> bf16 (P12). MODE 2 (transposed): +bias[row], softplus row<1024 -> fp32 CT.
template<int MODE>
__global__ __launch_bounds__(256)
void gemm128(const unsigned short* __restrict__ A, const unsigned short* __restrict__ Bt,
             void* __restrict__ Cv, const float* __restrict__ bias,
             int M, int N, int K)
{
  constexpr int BK = 64;
  constexpr int LPT = 8;                     // 4 A-segs + 4 B-segs per thread per stage
  __shared__ unsigned short As[2][128*BK];
  __shared__ unsigned short Bs[2][128*BK];
  int tid = threadIdx.x;
  int lane = tid & 63, wid = tid >> 6;
  int wm = wid >> 1, wn = wid & 1;

  // XCD-chunked bijective swizzle (grid.x*grid.y % 8 == 0)
  int gx = gridDim.x;
  int nwg = gx * gridDim.y;
  int L = blockIdx.y*gx + blockIdx.x;
  int W = (L & 7)*(nwg >> 3) + (L >> 3);
  int bx = W % gx, by = W / gx;
  int m0 = bx*128, n0 = by*128;

  f32x4 acc[4][4];
#pragma unroll
  for (int i=0;i<4;i++)
#pragma unroll
    for (int j=0;j<4;j++)
#pragma unroll
      for (int e=0;e<4;e++) acc[i][j][e] = 0.f;

  // seg s in [0,1024): row=s>>3, slot=s&7; slot holds source k-chunk slot^(row&7)
  const unsigned short* ap[4];
  const unsigned short* bp[4];
#pragma unroll
  for (int j=0;j<4;j++){
    int s = tid + j*256;
    int row = s >> 3, kc = ((s & 7) ^ (row & 7)) * 8;
    ap[j] = A + (size_t)(m0+row)*K + kc;
    bp[j] = Bt + (size_t)(n0+row)*K + kc;
  }

  auto stage = [&](int buf){
#pragma unroll
    for (int j=0;j<4;j++){
      __builtin_amdgcn_global_load_lds(AS1(ap[j]), AS3(&As[buf][(size_t)(j*256 + wid*64)*8]), 16, 0, 0);
      ap[j] += BK;
    }
#pragma unroll
    for (int j=0;j<4;j++){
      __builtin_amdgcn_global_load_lds(AS1(bp[j]), AS3(&Bs[buf][(size_t)(j*256 + wid*64)*8]), 16, 0, 0);
      bp[j] += BK;
    }
  };

  stage(0);
  stage(1);
  int T = K/BK;
  int r = lane & 15, kb = lane >> 4;
  for (int t = 0; t < T; ++t) {
    int rb = t & 1;
    if (t+1 < T) wait_vmcnt<LPT>();    // stage(t) landed; stage(t+1) in flight
    else         wait_vmcnt<0>();
    __builtin_amdgcn_s_barrier();      // buf rb fully staged for all waves
    short8 af[2][4], bfr[2][4];
#pragma unroll
    for (int ks=0; ks<2; ++ks) {
      int cx = (ks*4 + kb) ^ (r & 7);
#pragma unroll
      for (int i=0;i<4;i++){
        int row = wm*64 + i*16 + r;
        af[ks][i] = *(const short8*)&As[rb][(row*8 + cx)*8];
      }
#pragma unroll
      for (int j=0;j<4;j++){
        int row = wn*64 + j*16 + r;
        bfr[ks][j] = *(const short8*)&Bs[rb][(row*8 + cx)*8];
      }
    }
    asm volatile("s_waitcnt lgkmcnt(0)" ::: "memory");
    __builtin_amdgcn_sched_barrier(0);   // rule #18: don't hoist MFMA above the wait
    __builtin_amdgcn_s_barrier();        // all waves finished reading buf rb
    if (t+2 < T) stage(rb);              // refill rb with k-tile t+2
    __builtin_amdgcn_s_setprio(1);
#pragma unroll
    for (int ks=0; ks<2; ++ks)
#pragma unroll
      for (int i=0;i<4;i++)
#pragma unroll
        for (int j=0;j<4;j++)
          acc[i][j] = __builtin_amdgcn_mfma_f32_16x16x32_bf16(af[ks][i], bfr[ks][j], acc[i][j], 0,0,0);
    __builtin_amdgcn_s_setprio(0);
  }

  int rr = (lane >> 4)*4, cc = lane & 15;
#pragma unroll
  for (int i=0;i<4;i++)
#pragma unroll
    for (int j=0;j<4;j++) {
      int col = n0 + wn*64 + j*16 + cc;
      float bcol = (MODE == 1) ? bias[col] : 0.f;
#pragma unroll
      for (int e=0;e<4;e++) {
        int row = m0 + wm*64 + i*16 + rr + e;
        float v = acc[i][j][e];
        if constexpr (MODE == 2) {
          v += bias[row];
          if (row < 1024) v = softplusf(v);
          ((float*)Cv)[(size_t)row*N + col] = v;
        } else {
          ((unsigned short*)Cv)[(size_t)row*N + col] = f2bf(v + bcol);
        }
      }
    }
}

// ---------------- 64x64 bf16 GEMM, split-K partials (gemm3) ----------------
__global__ __launch_bounds__(256)
void gemm64s(const unsigned short* __restrict__ A, const unsigned short* __restrict__ Bt,
             float* __restrict__ Pp, int M, int N, int K, int Kfull)
{
  constexpr int BK = 64;
  constexpr int LPT = 4;
  __shared__ unsigned short As[3][64*BK];
  __shared__ unsigned short Bs[3][64*BK];
  int tid = threadIdx.x;
  int lane = tid & 63, wid = tid >> 6;
  int wm = wid >> 1, wn = wid & 1;
  int gx = gridDim.x;
  int nwg = gx * gridDim.y;
  int L = blockIdx.y*gx + blockIdx.x;
  int W = (L & 7)*(nwg >> 3) + (L >> 3);
  int bx = W % gx, by = W / gx;
  int m0 = bx*64, n0 = by*64;
  int kofs = blockIdx.z*K;

  f32x4 acc[2][2];
#pragma unroll
  for (int i=0;i<2;i++)
#pragma unroll
    for (int j=0;j<2;j++)
#pragma unroll
      for (int e=0;e<4;e++) acc[i][j][e] = 0.f;

  const unsigned short* ap[2];
  const unsigned short* bp[2];
#pragma unroll
  for (int j=0;j<2;j++){
    int s = tid + j*256;
    int row = s >> 3, kc = ((s & 7) ^ (row & 7)) * 8;
    ap[j] = A + (size_t)(m0+row)*Kfull + kofs + kc;
    bp[j] = Bt + (size_t)(n0+row)*Kfull + kofs + kc;
  }
  auto stage = [&](int buf){
#pragma unroll
    for (int j=0;j<2;j++){
      __builtin_amdgcn_global_load_lds(AS1(ap[j]), AS3(&As[buf][(size_t)(j*256 + wid*64)*8]), 16, 0, 0);
      ap[j] += BK;
    }
#pragma unroll
    for (int j=0;j<2;j++){
      __builtin_amdgcn_global_load_lds(AS1(bp[j]), AS3(&Bs[buf][(size_t)(j*256 + wid*64)*8]), 16, 0, 0);
      bp[j] += BK;
    }
  };
  stage(0); stage(1);
  int T = K/BK;
  int rb = 0, wb = 2;
  int r = lane & 15, kb = lane >> 4;
  for (int t = 0; t < T; ++t) {
    if (t+1 < T) wait_vmcnt<LPT>();
    else         wait_vmcnt<0>();
    __builtin_amdgcn_s_barrier();
    if (t+2 < T) { stage(wb); wb = (wb==2)?0:wb+1; }
#pragma unroll
    for (int ks=0; ks<2; ++ks) {
      int cx = (ks*4 + kb) ^ (r & 7);
      short8 af[2], bfr[2];
#pragma unroll
      for (int i=0;i<2;i++) af[i]  = *(const short8*)&As[rb][((wm*32 + i*16 + r)*8 + cx)*8];
#pragma unroll
      for (int j=0;j<2;j++) bfr[j] = *(const short8*)&Bs[rb][((wn*32 + j*16 + r)*8 + cx)*8];
      __builtin_amdgcn_s_setprio(1);
#pragma unroll
      for (int i=0;i<2;i++)
#pragma unroll
        for (int j=0;j<2;j++)
          acc[i][j] = __builtin_amdgcn_mfma_f32_16x16x32_bf16(af[i], bfr[j], acc[i][j], 0,0,0);
      __builtin_amdgcn_s_setprio(0);
    }
    rb = (rb==2)?0:rb+1;
  }
  int rr = (lane >> 4)*4, cc = lane & 15;
#pragma unroll
  for (int i=0;i<2;i++)
#pragma unroll
    for (int j=0;j<2;j++) {
      int col = n0 + wn*32 + j*16 + cc;
#pragma unroll
      for (int e=0;e<4;e++) {
        int row = m0 + wm*32 + i*16 + rr + e;
        Pp[(size_t)blockIdx.z*M*N + (size_t)row*N + col] = acc[i][j][e];
      }
    }
}

// ---------------- split-K reduce + bias + residual ----------------
__global__ __launch_bounds__(256)
void reduce_kernel(const float* __restrict__ P, const float* __restrict__ x,
                   const float* __restrict__ b3, float* __restrict__ out)
{
  size_t i = ((size_t)blockIdx.x*256 + threadIdx.x)*4;
  int col = (int)(i & 511);
  float4 a = *(const float4*)&P[i];
  float4 b = *(const float4*)&P[(size_t)ROWS*512 + i];
  float4 xv = *(const float4*)&x[i];
  float4 bv = *(const float4*)&b3[col];
  float4 o;
  o.x = a.x + b.x + xv.x + bv.x;
  o.y = a.y + b.y + xv.y + bv.y;
  o.z = a.z + b.z + xv.z + bv.z;
  o.w = a.w + b.w + xv.w + bv.w;
  *(float4*)&out[i] = o;
}

// ---------------- causal depthwise conv (K=4) + SiLU; also SiLU for x2 (bf16 in) ----------------
__global__ __launch_bounds__(256)
void conv_silu_kernel(const unsigned short* __restrict__ P12, const float* __restrict__ ck,
                      const float* __restrict__ cb, unsigned short* __restrict__ ubf,
                      unsigned short* __restrict__ x2bf)
{
  int gid = blockIdx.x*256 + threadIdx.x;   // ROWS * 512 tasks
  int c4 = gid & 511;
  int row = gid >> 9;
  int l = row & (L_SEQ-1);
  if (c4 < 256) {
    int c = c4*4;
    float4 bv = *(const float4*)&cb[c];
    float r0=bv.x, r1=bv.y, r2=bv.z, r3=bv.w;
#pragma unroll
    for (int t=0;t<4;t++){
      int lsrc = l - 3 + t;
      if (lsrc >= 0) {
        ushort4 xv = *(const ushort4*)&P12[(size_t)(row-3+t)*2048 + c];
        float4 kv = *(const float4*)&ck[t*PROJ + c];
        r0 = fmaf(bf2f(xv.x),kv.x,r0);
        r1 = fmaf(bf2f(xv.y),kv.y,r1);
        r2 = fmaf(bf2f(xv.z),kv.z,r2);
        r3 = fmaf(bf2f(xv.w),kv.w,r3);
      }
    }
    ushort4 o;
    o.x=f2bf(siluf(r0)); o.y=f2bf(siluf(r1)); o.z=f2bf(siluf(r2)); o.w=f2bf(siluf(r3));
    *(ushort4*)&ubf[(size_t)row*PROJ + c] = o;
  } else {
    int c = (c4-256)*4;
    ushort4 xv = *(const ushort4*)&P12[(size_t)row*2048 + 1024 + c];
    ushort4 o;
    o.x=f2bf(siluf(bf2f(xv.x))); o.y=f2bf(siluf(bf2f(xv.y)));
    o.z=f2bf(siluf(bf2f(xv.z))); o.w=f2bf(siluf(bf2f(xv.w)));
    *(ushort4*)&x2bf[(size_t)row*PROJ + c] = o;
  }
}

// ---------------- fused suffix-sum + windowed gated scan (bf16 ystate) ----------------
__global__ __launch_bounds__(256)
void sscan_kernel(const float* __restrict__ CT, const unsigned short* __restrict__ ubf,
                  const float* __restrict__ A_log, int* __restrict__ l0out,
                  unsigned short* __restrict__ ystate)
{
  __shared__ float suf8sh[8][256];
  int tid = threadIdx.x;
  int n = tid & 31, gsub = tid >> 5;
  int G = blockIdx.x*8 + gsub;
  int b = G >> 10, d = G & 1023;
  const float* dT = CT + (size_t)d*ROWS + b*L_SEQ;   // softplus'd delta row

  // phase A: lane n owns elements [n*64, n*64+64)
  float mysum = 0.f;
  {
    const float4* c4 = (const float4*)(dT + n*64);
    for (int it=0; it<16; ++it){ float4 v = c4[it]; mysum += v.x+v.y+v.z+v.w; }
  }
  float incl = mysum;
#pragma unroll
  for (int dlt=1; dlt<32; dlt<<=1){ float t = __shfl_up(incl, dlt, 32); if (n >= dlt) incl += t; }
  float Tot = __shfl(incl, 31, 32);
  float excl = incl - mysum;
  int cnt = 0;
  {
    const float4* c4 = (const float4*)(dT + n*64);
    float run = excl;
    for (int it=0; it<16; ++it){
      float4 v = c4[it];
      if ((it & 1) == 0) suf8sh[gsub][n*8 + (it>>1)] = Tot - run;
      cnt += (Tot - run >= THRESH); run += v.x;
      cnt += (Tot - run >= THRESH); run += v.y;
      cnt += (Tot - run >= THRESH); run += v.z;
      cnt += (Tot - run >= THRESH); run += v.w;
    }
  }
#pragma unroll
  for (int m=16;m>0;m>>=1) cnt += __shfl_xor(cnt, m, 32);
  int myl0 = cnt > 0 ? cnt-1 : 0;
  if (n == 0) l0out[G] = myl0;
  __syncthreads();

  // phase B
  int base = min(myl0, __shfl_xor(myl0, 32)) & ~7;   // wave-uniform, 8-aligned
  float np1 = __expf(A_log[d*NST + n]);              // -A[d,n] = n+1
  const float* Br = CT + (size_t)(1024+n)*ROWS + b*L_SEQ;
  const float* Cr = CT + (size_t)(1056+n)*ROWS + b*L_SEQ;
  const unsigned short* ub = ubf + (size_t)b*L_SEQ*PROJ + d;
  unsigned short* yb = ystate + (size_t)b*L_SEQ*PROJ + d;
  float s = 0.f;
  for (int l = base; l < L_SEQ; l += 8) {
    float4 d0 = *(const float4*)&dT[l];
    float4 d1 = *(const float4*)&dT[l+4];
    float4 B0 = *(const float4*)&Br[l];
    float4 B1 = *(const float4*)&Br[l+4];
    float4 C0 = *(const float4*)&Cr[l];
    float4 C1 = *(const float4*)&Cr[l+4];
    float sufv = suf8sh[gsub][l >> 3];               // suffix incl. position l
    float dl[8] = {d0.x,d0.y,d0.z,d0.w,d1.x,d1.y,d1.z,d1.w};
    float Bv[8] = {B0.x,B0.y,B0.z,B0.w,B1.x,B1.y,B1.z,B1.w};
    float Cv[8] = {C0.x,C0.y,C0.z,C0.w,C1.x,C1.y,C1.z,C1.w};
    float uu[8];
#pragma unroll
    for (int t=0;t<8;t++) uu[t] = bf2f(ub[(size_t)(l+t)*PROJ]);
    float cum = 0.f;
#pragma unroll
    for (int t=0;t<8;t++){
      cum += dl[t];
      float decay = __expf(-dl[t]*np1);
      s = fmaf(decay, s, dl[t]*uu[t]*Bv[t]);
      float gte = 1.f/(1.f + 1e-12f*__expf(np1*(sufv - cum)));  // overflow->inf->0
      float contrib = s*gte*Cv[t];
#pragma unroll
      for (int m=16;m>0;m>>=1) contrib += __shfl_xor(contrib, m);
      if (n == 0) yb[(size_t)(l+t)*PROJ] = f2bf(contrib);
    }
  }
}

// ---------------- z = (ystate_gated + u*D_skip) * x2 -> bf16 (l0-gated) ----------------
__global__ __launch_bounds__(256)
void zmul_kernel(const unsigned short* __restrict__ ystate, const unsigned short* __restrict__ ubf,
                 const unsigned short* __restrict__ x2bf, const float* __restrict__ Dskip,
                 const int* __restrict__ l0arr, unsigned short* __restrict__ zbf)
{
  size_t i = ((size_t)blockIdx.x*256 + threadIdx.x)*4;
  int d = (int)(i & (PROJ-1));
  int row = (int)(i >> 10);
  int l = row & (L_SEQ-1);
  int b = row >> 11;
  int4 l0v = *(const int4*)&l0arr[b*PROJ + d];
  ushort4 yu = *(const ushort4*)&ystate[i];
  float ysx = (l >= l0v.x) ? bf2f(yu.x) : 0.f;
  float ysy = (l >= l0v.y) ? bf2f(yu.y) : 0.f;
  float ysz = (l >= l0v.z) ? bf2f(yu.z) : 0.f;
  float ysw = (l >= l0v.w) ? bf2f(yu.w) : 0.f;
  ushort4 uu = *(const ushort4*)&ubf[i];
  ushort4 xx = *(const ushort4*)&x2bf[i];
  float4 Dv = *(const float4*)&Dskip[d];
  ushort4 o;
  o.x = f2bf((ysx + bf2f(uu.x)*Dv.x)*bf2f(xx.x));
  o.y = f2bf((ysy + bf2f(uu.y)*Dv.y)*bf2f(xx.y));
  o.z = f2bf((ysz + bf2f(uu.z)*Dv.z)*bf2f(xx.z));
  o.w = f2bf((ysw + bf2f(uu.w)*Dv.w)*bf2f(xx.w));
  *(ushort4*)&zbf[i] = o;
}

extern "C" void kernel_launch(void* const* d_in, const int* in_sizes, int n_in,
                              void* d_out, int out_size, void* d_ws, size_t ws_size,
                              hipStream_t stream)
{
  const float* x     = (const float*)d_in[0];
  const float* ln_g  = (const float*)d_in[1];
  const float* ln_b  = (const float*)d_in[2];
  const float* W1    = (const float*)d_in[3];
  const float* b1    = (const float*)d_in[4];
  const float* W2    = (const float*)d_in[5];
  const float* b2    = (const float*)d_in[6];
  const float* convk = (const float*)d_in[7];
  const float* convb = (const float*)d_in[8];
  const float* A_log = (const float*)d_in[9];
  const float* Dskip = (const float*)d_in[10];
  const float* WB    = (const float*)d_in[11];
  const float* bB    = (const float*)d_in[12];
  const float* WC    = (const float*)d_in[13];
  const float* bC    = (const float*)d_in[14];
  const float* Wd    = (const float*)d_in[15];
  const float* bd    = (const float*)d_in[16];
  const float* W3    = (const float*)d_in[17];
  const float* b3    = (const float*)d_in[18];

  char* w = (char*)d_ws;
  auto alloc = [&](size_t bytes){ char* p = w; w += (bytes + 255) & ~(size_t)255; return p; };
  unsigned short* Hbf    = (unsigned short*)alloc((size_t)ROWS*DMODEL*2);
  unsigned short* W12t   = (unsigned short*)alloc((size_t)2048*512*2);
  unsigned short* Wcatt  = (unsigned short*)alloc((size_t)NCAT*1024*2);
  unsigned short* W3t    = (unsigned short*)alloc((size_t)512*1024*2);
  float*          bias12 = (float*)alloc(2048*4);
  float*          biascat= (float*)alloc(NCAT*4);
  unsigned short* P12    = (unsigned short*)alloc((size_t)ROWS*2048*2);
  unsigned short* ubf    = (unsigned short*)alloc((size_t)ROWS*PROJ*2);
  unsigned short* x2bf   = (unsigned short*)alloc((size_t)ROWS*PROJ*2);
  float*          CT     = (float*)alloc((size_t)NCAT*ROWS*4);
  int*            l0arr  = (int*)alloc(2048*4);
  unsigned short* ystate = (unsigned short*)alloc((size_t)ROWS*PROJ*2);
  unsigned short* zbf    = (unsigned short*)alloc((size_t)ROWS*PROJ*2);
  float*          Pp     = (float*)alloc((size_t)2*ROWS*512*4);

  prep_kernel<<<2701, 256, 0, stream>>>(W1,b1,W2,b2,Wd,bd,WB,bB,WC,bC,W3,
                                        W12t,Wcatt,W3t,bias12,biascat);
  ln_kernel<<<ROWS/4, 256, 0, stream>>>(x, ln_g, ln_b, Hbf);

  // gemm1: P12[4096][2048] = Hbf x W12t^T   (512 blocks, 2/CU)
  dim3 g1(ROWS/128, 2048/128);
  gemm128<1><<<g1, 256, 0, stream>>>(Hbf, W12t, P12, bias12, ROWS, 2048, DMODEL);

  conv_silu_kernel<<<ROWS*512/256, 256, 0, stream>>>(P12, convk, convb, ubf, x2bf);

  // gemm2 (transposed out): CT[1152][4096] = Wcatt x ubf^T   (288 blocks)
  dim3 g2(NCAT/128, ROWS/128);
  gemm128<2><<<g2, 256, 0, stream>>>(Wcatt, ubf, CT, biascat, NCAT, ROWS, PROJ);

  sscan_kernel<<<2048/8, 256, 0, stream>>>(CT, ubf, A_log, l0arr, ystate);

  zmul_kernel<<<(ROWS*PROJ/4)/256, 256, 0, stream>>>(ystate, ubf, x2bf, Dskip, l0arr, zbf);

  // gemm3 split-K=2 (1024 blocks), then reduce(+bias+residual)
  dim3 g3(ROWS/64, 512/64, 2);
  gemm64s<<<g3, 256, 0, stream>>>(zbf, W3t, Pp, ROWS, 512, 512, PROJ);
  reduce_kernel<<<(ROWS*512/4)/256, 256, 0, stream>>>(Pp, x, b3, (float*)d_out);
}